// Round 8
// baseline (883.953 us; speedup 1.0000x reference)
//
#include <hip/hip_runtime.h>
#include <hip/hip_bf16.h>

// B=64, T=60 (40 enc + 20 dec), H=512, E=512, V=32000. fp32 I/O.
// Compute: bf16 MFMA (fp32 accum), on-the-fly fp32->bf16 in staging.
//
// r8 structure (overlap path, requires ws >= ~65.6MB):
//   1) cvt_bf16: W_lin fp32 -> bf16 (wbf in ws).
//   2) gemm_xproj: Xp = xs @ W_ih^T + b  (Xp now in WS, not d_out, so the
//      megakernel's consumers can write `out` while the LSTM still reads Xp).
//   3) mega (ONE dispatch, 32+2500 blocks):
//        blocks 0..31   : persistent LSTM (verbatim r7 body; dec_h written
//                         slice-major [(t-40)*64+b][512] with agent-scope
//                         write-through stores; final flag=59 after t=58).
//        blocks 32..2531: gemm_out consumer tiles. Tile (mt,nt) spins
//                         (s_sleep(32), bounded) until all 32 flags >=
//                         42+2*mt (its dec_h slices are at the coherence
//                         point), loads its 128x512 A-slab ONCE via L2-bypass
//                         atomic loads into LDS (XOR-swizzled), then runs the
//                         K-loop with r7's swizzled global_load_lds B staging.
//                         C rows permuted back to b*19+dec order.
//      LSTM blocks have the lowest block IDs -> dispatched first into an
//      empty machine -> resident before any consumer can occupy CUs (LDS
//      144KB/block => 1 block/CU everywhere).
//   Fallback (ws < 65.6MB): Xp in d_out, mega launched with grid=32 (LSTM
//   only), then standalone gemm_out (r7's) — i.e. the measured r7 pipeline.

typedef short bf16x8 __attribute__((ext_vector_type(8)));
typedef float f32x4 __attribute__((ext_vector_type(4)));

__device__ inline short f2bf(float f) {
    unsigned u = __float_as_uint(f);
    unsigned r = (u + 0x7fffu + ((u >> 16) & 1u)) >> 16;   // RNE
    return (short)r;
}
__device__ inline int4 ld8_f32_to_bf16(const float* __restrict__ g) {
    float4 a = *(const float4*)g;
    float4 b = *(const float4*)(g + 4);
    union { short s[8]; int4 v; } u;
    u.s[0] = f2bf(a.x); u.s[1] = f2bf(a.y); u.s[2] = f2bf(a.z); u.s[3] = f2bf(a.w);
    u.s[4] = f2bf(b.x); u.s[5] = f2bf(b.y); u.s[6] = f2bf(b.z); u.s[7] = f2bf(b.w);
    return u.v;
}
__device__ inline float sig_fast(float x) {
    return __builtin_amdgcn_rcpf(1.0f + __expf(-x));
}
__device__ inline float tanh_fast(float x) {
    return 1.0f - 2.0f * __builtin_amdgcn_rcpf(1.0f + __expf(2.0f * x));
}
__device__ inline void gload_lds16(const void* g, void* l) {
    __builtin_amdgcn_global_load_lds(
        (const __attribute__((address_space(1))) void*)g,
        (__attribute__((address_space(3))) void*)l, 16, 0, 0);
}

// ---------------------------------------------------------------------------
// GEMM1 (fused xs build): Xp[3840][2048] = xs @ W_ih^T + (b_ih + b_hh), fp32.
// ---------------------------------------------------------------------------
__global__ __launch_bounds__(256) void gemm_xproj(
    const float* __restrict__ feature,    // [64][60][512]
    const int*   __restrict__ captions,   // [64][20]
    const float* __restrict__ embedding,  // [32000][512]
    const float* __restrict__ W_ih,       // [2048][1024]
    const float* __restrict__ b_ih,
    const float* __restrict__ b_hh,
    float* __restrict__ Xp)               // [3840][2048]
{
    __shared__ __align__(16) short Al[128 * 72];
    __shared__ __align__(16) short Bl[128 * 72];
    const int tid  = threadIdx.x;
    const int wave = tid >> 6, lane = tid & 63;
    const int quad = lane >> 4, l16 = lane & 15;
    const int m0 = blockIdx.y * 128;
    const int n0 = blockIdx.x * 128;
    const int wm = (wave >> 1) * 64, wn = (wave & 1) * 64;
    const int sr = tid >> 3;
    const int sc = (tid & 7) * 8;

    f32x4 acc[4][4] = {};

    for (int k0 = 0; k0 < 1024; k0 += 64) {
        const int j = k0 + sc;
#pragma unroll
        for (int p = 0; p < 4; ++p) {
            int r = sr + p * 32;
            int row = m0 + r;
            int t = row >> 6, b = row & 63;
            int4 val;
            if (j < 512) {
                if (t >= 40) {
                    int tok = captions[b * 20 + (t - 40)];
                    val = ld8_f32_to_bf16(&embedding[(size_t)tok * 512 + j]);
                } else {
                    val = make_int4(0, 0, 0, 0);
                }
            } else {
                val = ld8_f32_to_bf16(&feature[(size_t)(b * 60 + t) * 512 + (j - 512)]);
            }
            *(int4*)&Al[r * 72 + sc] = val;
            *(int4*)&Bl[r * 72 + sc] = ld8_f32_to_bf16(&W_ih[(size_t)(n0 + r) * 1024 + j]);
        }
        __syncthreads();
#pragma unroll
        for (int kk = 0; kk < 64; kk += 32) {
            bf16x8 af[4], bg[4];
#pragma unroll
            for (int i = 0; i < 4; ++i)
                af[i] = *(const bf16x8*)&Al[(wm + i * 16 + l16) * 72 + kk + quad * 8];
#pragma unroll
            for (int jj = 0; jj < 4; ++jj)
                bg[jj] = *(const bf16x8*)&Bl[(wn + jj * 16 + l16) * 72 + kk + quad * 8];
#pragma unroll
            for (int i = 0; i < 4; ++i)
#pragma unroll
                for (int jj = 0; jj < 4; ++jj)
                    acc[i][jj] = __builtin_amdgcn_mfma_f32_16x16x32_bf16(
                        af[i], bg[jj], acc[i][jj], 0, 0, 0);
        }
        __syncthreads();
    }

#pragma unroll
    for (int jj = 0; jj < 4; ++jj) {
        int n = n0 + wn + jj * 16 + l16;
        float bv = b_ih[n] + b_hh[n];
#pragma unroll
        for (int i = 0; i < 4; ++i) {
            int mbase = m0 + wm + i * 16 + quad * 4;
#pragma unroll
            for (int r = 0; r < 4; ++r)
                Xp[(size_t)(mbase + r) * 2048 + n] = acc[i][jj][r] + bv;
        }
    }
}

// ---------------------------------------------------------------------------
// W_lin fp32 -> bf16 pre-convert
// ---------------------------------------------------------------------------
__global__ __launch_bounds__(256) void cvt_bf16(
    const float* __restrict__ src, short* __restrict__ dst, int n8)
{
    int i = blockIdx.x * 256 + threadIdx.x;
    if (i < n8)
        *(int4*)&dst[(size_t)i * 8] = ld8_f32_to_bf16(&src[(size_t)i * 8]);
}

// ---------------------------------------------------------------------------
// Standalone GEMM2 (serial fallback only): out = A(slice-major bf16) @ W^T +
// bias; C rows permuted (A row = dec*64+b -> C row = b*19+dec). BF16B: r7's
// swizzled global_load_lds staging; else reg-staged fp32 conversion.
// ---------------------------------------------------------------------------
template <bool BF16B>
__global__ __launch_bounds__(256) void gemm_out(
    const short* __restrict__ A,       // M x K bf16, slice-major rows
    const void*  __restrict__ Wv,      // N x K (bf16 or f32)
    const float* __restrict__ bias,    // N
    float* __restrict__ C,
    int M, int N, int K)
{
    __shared__ __align__(16) short Al[128 * 72];
    __shared__ __align__(16) short Bl[128 * 72];
    const int tid  = threadIdx.x;
    const int wave = tid >> 6, lane = tid & 63;
    const int quad = lane >> 4, l16 = lane & 15;
    const int m0 = blockIdx.y * 128;
    const int n0 = blockIdx.x * 128;
    const int wm = (wave >> 1) * 64, wn = (wave & 1) * 64;
    const int sr = tid >> 3;
    const int sc = (tid & 7) * 8;

    f32x4 acc[4][4] = {};

    for (int k0 = 0; k0 < K; k0 += 64) {
        if (BF16B) {
            const char* Ab = (const char*)A;
            const char* Wb = (const char*)Wv;
            char* AlB = (char*)Al;
            char* BlB = (char*)Bl;
#pragma unroll
            for (int p = 0; p < 4; ++p) {
                int row = p * 32 + wave * 8 + (lane >> 3);
                int ss  = ((lane & 7) ^ (row & 7)) << 4;
                int am  = m0 + row; am = (am < M) ? am : (M - 1);
                gload_lds16(Ab + (size_t)am * 1024 + k0 * 2 + ss,
                            AlB + p * 4096 + wave * 1024);
                gload_lds16(Wb + (size_t)(n0 + row) * 1024 + k0 * 2 + ss,
                            BlB + p * 4096 + wave * 1024);
            }
        } else {
#pragma unroll
            for (int p = 0; p < 4; ++p) {
                int r = sr + p * 32;
                int am = m0 + r;
                am = (am < M) ? am : (M - 1);
                *(int4*)&Al[r * 72 + sc] = *(const int4*)&A[(size_t)am * K + k0 + sc];
                *(int4*)&Bl[r * 72 + sc] =
                    ld8_f32_to_bf16(&((const float*)Wv)[(size_t)(n0 + r) * K + k0 + sc]);
            }
        }
        __syncthreads();
#pragma unroll
        for (int kk = 0; kk < 64; kk += 32) {
            bf16x8 af[4], bg[4];
            if (BF16B) {
                const int s_ = (kk >> 3) + quad;
#pragma unroll
                for (int i = 0; i < 4; ++i) {
                    int rw = wm + i * 16 + l16;
                    af[i] = *(const bf16x8*)&Al[rw * 64 + ((s_ ^ (rw & 7)) << 3)];
                }
#pragma unroll
                for (int jj = 0; jj < 4; ++jj) {
                    int rw = wn + jj * 16 + l16;
                    bg[jj] = *(const bf16x8*)&Bl[rw * 64 + ((s_ ^ (rw & 7)) << 3)];
                }
            } else {
#pragma unroll
                for (int i = 0; i < 4; ++i)
                    af[i] = *(const bf16x8*)&Al[(wm + i * 16 + l16) * 72 + kk + quad * 8];
#pragma unroll
                for (int jj = 0; jj < 4; ++jj)
                    bg[jj] = *(const bf16x8*)&Bl[(wn + jj * 16 + l16) * 72 + kk + quad * 8];
            }
#pragma unroll
            for (int i = 0; i < 4; ++i)
#pragma unroll
                for (int jj = 0; jj < 4; ++jj)
                    acc[i][jj] = __builtin_amdgcn_mfma_f32_16x16x32_bf16(
                        af[i], bg[jj], acc[i][jj], 0, 0, 0);
        }
        __syncthreads();
    }

#pragma unroll
    for (int jj = 0; jj < 4; ++jj) {
        int n = n0 + wn + jj * 16 + l16;
        float bv = bias[n];
#pragma unroll
        for (int i = 0; i < 4; ++i) {
            int mbase = m0 + wm + i * 16 + quad * 4;
#pragma unroll
            for (int r = 0; r < 4; ++r) {
                int ar = mbase + r;
                if (ar < M) {
                    int crow = (ar & 63) * 19 + (ar >> 6);   // b*19 + dec
                    C[(size_t)crow * N + n] = acc[i][jj][r] + bv;
                }
            }
        }
    }
}

// ---------------------------------------------------------------------------
// MEGA: blocks 0..31 persistent LSTM; blocks 32.. gemm_out consumers.
// ---------------------------------------------------------------------------
#define LSTM_BLOCKS 32

__global__ __launch_bounds__(256, 1) void mega(
    const float* __restrict__ Xp,     // [59][64][2048] fp32
    const float* __restrict__ W_hh,   // [2048][512] fp32
    unsigned long long* __restrict__ hbuf,  // [2][64][512] bf16 ping-pong
    unsigned long long* __restrict__ dec_h, // [(t-40)*64+b][512] bf16 as u64
    unsigned* __restrict__ flags,     // [32] zeroed per launch
    const short* __restrict__ wbf,    // [32000][512] bf16 (overlap path only)
    const float* __restrict__ b_lin,  // [32000]
    float* __restrict__ out)          // [1216][32000] fp32
{
    __shared__ __align__(16) char smem[147456];
    const int tid  = threadIdx.x;
    const int wave = tid >> 6, lane = tid & 63;
    const int quad = lane >> 4, l16 = lane & 15;

    if (blockIdx.x < LSTM_BLOCKS) {
        // ================= LSTM (verbatim r7 body; dec_h slice-major) ======
        short* Wl  = (short*)smem;                 // 64 KB, swizzled
        short* Htb = (short*)(smem + 65536);       // 2 KB: 4 waves x 16 x 16
        const int nb = blockIdx.x * 16;
        const int swz = (l16 & 7) << 3;

#pragma unroll
        for (int it = 0; it < 16; ++it) {
            int rr = (tid >> 6) + it * 4;
            int k  = (tid & 63) * 8;
            int s = rr >> 4, col = rr & 15;
            *(int4*)&Wl[(rr * 512 + k) ^ ((rr & 7) << 3)] =
                ld8_f32_to_bf16(&W_hh[(size_t)(s * 512 + nb + col) * 512 + k]);
        }
        float creg[4] = {0.f, 0.f, 0.f, 0.f};

        const int n = nb + l16;
        float xg[4][4];
#pragma unroll
        for (int r = 0; r < 4; ++r) {
            const float* xr = Xp + (size_t)(wave * 16 + quad * 4 + r) * 2048;
            xg[r][0] = xr[n];
            xg[r][1] = xr[512 + n];
            xg[r][2] = xr[1024 + n];
            xg[r][3] = xr[1536 + n];
        }
        __syncthreads();

        for (int t = 0; t < 59; ++t) {
            f32x4 acc[4] = {};
            if (t > 0) {
                const unsigned long long* hrow =
                    hbuf + ((size_t)((t & 1) ^ 1) << 13)
                         + (size_t)(wave * 16 + l16) * 128 + quad * 2;
                union { unsigned long long q[2]; bf16x8 v; } hu[16];
#pragma unroll
                for (int kk = 0; kk < 16; ++kk) {
                    hu[kk].q[0] = __hip_atomic_load(&hrow[kk * 8],
                                     __ATOMIC_RELAXED, __HIP_MEMORY_SCOPE_AGENT);
                    hu[kk].q[1] = __hip_atomic_load(&hrow[kk * 8 + 1],
                                     __ATOMIC_RELAXED, __HIP_MEMORY_SCOPE_AGENT);
                }
                __builtin_amdgcn_sched_barrier(0);
#pragma unroll
                for (int kk = 0; kk < 16; ++kk) {
#pragma unroll
                    for (int s = 0; s < 4; ++s) {
                        bf16x8 bg = *(const bf16x8*)
                            &Wl[((s * 16 + l16) * 512 + kk * 32 + quad * 8) ^ swz];
                        acc[s] = __builtin_amdgcn_mfma_f32_16x16x32_bf16(
                            hu[kk].v, bg, acc[s], 0, 0, 0);
                    }
                }
            }
#pragma unroll
            for (int r = 0; r < 4; ++r) {
                float iv = acc[0][r] + xg[r][0];
                float fv = acc[1][r] + xg[r][1];
                float gv = acc[2][r] + xg[r][2];
                float ov = acc[3][r] + xg[r][3];
                float cn = sig_fast(fv) * creg[r] + sig_fast(iv) * tanh_fast(gv);
                float hn = sig_fast(ov) * tanh_fast(cn);
                creg[r] = cn;
                Htb[(wave << 8) + ((quad * 4 + r) << 4) + l16] = f2bf(hn);
            }
            asm volatile("s_waitcnt lgkmcnt(0)" ::: "memory");
            unsigned long long* hout64 = hbuf + ((size_t)(t & 1) << 13);
            {
                int row = lane >> 2, qp = lane & 3;
                unsigned long long v =
                    *(const unsigned long long*)&Htb[(wave << 8) + (row << 4) + qp * 4];
                int m = wave * 16 + row;
                __hip_atomic_store(&hout64[m * 128 + (nb >> 2) + qp], v,
                                   __ATOMIC_RELAXED, __HIP_MEMORY_SCOPE_AGENT);
                if (t >= 40)
                    __hip_atomic_store(
                        &dec_h[(size_t)((t - 40) * 64 + m) * 128 + (nb >> 2) + qp], v,
                        __ATOMIC_RELAXED, __HIP_MEMORY_SCOPE_AGENT);
            }
            if (t < 58) {
                float xn_[4][4];
                const float* xt = Xp + (size_t)(t + 1) * 131072;
#pragma unroll
                for (int r = 0; r < 4; ++r) {
                    const float* xr = xt + (size_t)(wave * 16 + quad * 4 + r) * 2048;
                    xn_[r][0] = xr[n];
                    xn_[r][1] = xr[512 + n];
                    xn_[r][2] = xr[1024 + n];
                    xn_[r][3] = xr[1536 + n];
                }
                __syncthreads();   // drains vmcnt(0): h+dec_h at coherence pt
                if (tid == 0)
                    __hip_atomic_store(&flags[blockIdx.x], (unsigned)(t + 1),
                                       __ATOMIC_RELAXED, __HIP_MEMORY_SCOPE_AGENT);
                if (tid < LSTM_BLOCKS) {
                    int guard = 0;
                    while (__hip_atomic_load(&flags[tid], __ATOMIC_RELAXED,
                                             __HIP_MEMORY_SCOPE_AGENT) < (unsigned)(t + 1)
                           && guard < (1 << 16)) {
                        __builtin_amdgcn_s_sleep(1);
                        ++guard;
                    }
                }
                __syncthreads();
#pragma unroll
                for (int r = 0; r < 4; ++r)
#pragma unroll
                    for (int g = 0; g < 4; ++g)
                        xg[r][g] = xn_[r][g];
            }
        }
        // final publish: slice 18 (t=58) visible -> flag 59
        __syncthreads();           // drains t=58 dec_h/h stores
        if (tid == 0)
            __hip_atomic_store(&flags[blockIdx.x], 59u,
                               __ATOMIC_RELAXED, __HIP_MEMORY_SCOPE_AGENT);
        return;
    }

    // ================= consumer: one 128x128 tile of out ===================
    short* As = (short*)smem;                      // 128 x 512, swizzled (128KB)
    short* Bt = (short*)(smem + 131072);           // 128 x 64 per k0 (16KB)
    const int cid = blockIdx.x - LSTM_BLOCKS;
    const int n0 = (cid % 250) * 128;
    const int mt = cid / 250;
    const int m0 = mt * 128;
    const int M = 1216;
    const int wm = (wave >> 1) * 64, wn = (wave & 1) * 64;
    int maxa = m0 + 127; maxa = (maxa < M - 1) ? maxa : (M - 1);
    const unsigned v = 41u + (unsigned)(maxa >> 6);   // flags threshold

    // wait until all LSTM blocks have published the needed slices
    if (tid < LSTM_BLOCKS) {
        int guard = 0;
        while (__hip_atomic_load(&flags[tid], __ATOMIC_RELAXED,
                                 __HIP_MEMORY_SCOPE_AGENT) < v
               && guard < (1 << 14)) {
            __builtin_amdgcn_s_sleep(32);          // coarse poll
            ++guard;
        }
    }
    __syncthreads();

    // A-slab: dec_h rows m0..m0+127 (clamped), 512 shorts each, L2-bypass
    // loads -> LDS with the lstm-style XOR swizzle (row stride 1024B).
    {
        int row = tid >> 1, half = tid & 1;        // row 0..127
        int ar = m0 + row; ar = (ar < M) ? ar : (M - 1);
        const unsigned long long* g = dec_h + (size_t)ar * 128 + half * 64;
        const int cbase = half * 256;              // shorts
#pragma unroll
        for (int j = 0; j < 32; ++j) {             // 32 x 16B chunks
            union { unsigned long long q[2]; int4 v4; } u;
            u.q[0] = __hip_atomic_load(&g[j * 2],
                         __ATOMIC_RELAXED, __HIP_MEMORY_SCOPE_AGENT);
            u.q[1] = __hip_atomic_load(&g[j * 2 + 1],
                         __ATOMIC_RELAXED, __HIP_MEMORY_SCOPE_AGENT);
            int off = (row * 512 + cbase + j * 8) ^ ((row & 7) << 3);
            *(int4*)&As[off] = u.v4;
        }
    }

    f32x4 acc[4][4] = {};
    const char* Wb = (const char*)wbf;             // row stride 1024 B
    char* BtB = (char*)Bt;
    const int swzA = (l16 & 7) << 3;

    for (int k0 = 0; k0 < 512; k0 += 64) {
        // stage B via swizzled global_load_lds (r7-proven pattern)
#pragma unroll
        for (int p = 0; p < 4; ++p) {
            int row = p * 32 + wave * 8 + (lane >> 3);
            int ss  = ((lane & 7) ^ (row & 7)) << 4;
            gload_lds16(Wb + (size_t)(n0 + row) * 1024 + k0 * 2 + ss,
                        BtB + p * 4096 + wave * 1024);
        }
        __syncthreads();   // B ready; iter0: A-slab ds_writes drained too
#pragma unroll
        for (int kk = 0; kk < 64; kk += 32) {
            bf16x8 af[4], bg[4];
            const int s_ = (kk >> 3) + quad;
#pragma unroll
            for (int i = 0; i < 4; ++i) {
                int rw = wm + i * 16 + l16;
                af[i] = *(const bf16x8*)&As[(rw * 512 + k0 + kk + quad * 8) ^ swzA];
            }
#pragma unroll
            for (int jj = 0; jj < 4; ++jj) {
                int rw = wn + jj * 16 + l16;
                bg[jj] = *(const bf16x8*)&Bt[rw * 64 + ((s_ ^ (rw & 7)) << 3)];
            }
#pragma unroll
            for (int i = 0; i < 4; ++i)
#pragma unroll
                for (int jj = 0; jj < 4; ++jj)
                    acc[i][jj] = __builtin_amdgcn_mfma_f32_16x16x32_bf16(
                        af[i], bg[jj], acc[i][jj], 0, 0, 0);
        }
        __syncthreads();   // before next B overwrite
    }

#pragma unroll
    for (int jj = 0; jj < 4; ++jj) {
        int n = n0 + wn + jj * 16 + l16;
        float bv = b_lin[n];
#pragma unroll
        for (int i = 0; i < 4; ++i) {
            int mbase = m0 + wm + i * 16 + quad * 4;
#pragma unroll
            for (int r = 0; r < 4; ++r) {
                int ar = mbase + r;
                if (ar < M) {
                    int crow = (ar & 63) * 19 + (ar >> 6);   // b*19 + dec
                    out[(size_t)crow * 32000 + n] = acc[i][jj][r] + bv;
                }
            }
        }
    }
}

// ---------------------------------------------------------------------------
extern "C" void kernel_launch(void* const* d_in, const int* in_sizes, int n_in,
                              void* d_out, int out_size, void* d_ws, size_t ws_size,
                              hipStream_t stream)
{
    (void)in_sizes; (void)n_in; (void)out_size;
    const float* feature   = (const float*)d_in[0];
    const int*   captions  = (const int*)d_in[1];
    const float* embedding = (const float*)d_in[2];
    const float* W_ih      = (const float*)d_in[3];
    const float* W_hh      = (const float*)d_in[4];
    const float* b_ih      = (const float*)d_in[5];
    const float* b_hh      = (const float*)d_in[6];
    const float* W_lin     = (const float*)d_in[7];
    const float* b_lin     = (const float*)d_in[8];
    float* out = (float*)d_out;

    // ws layout
    char* ws = (char*)d_ws;
    unsigned long long* hbuf = (unsigned long long*)(ws);   // 131,072 B
    unsigned long long* dech = (unsigned long long*)(ws + 131072); // 1,245,184 B
    unsigned* flags = (unsigned*)(ws + 1376256);            // 256 B
    short*    wbf   = (short*)(ws + 1376512);               // 32,768,000 B
    float*    xpws  = (float*)(ws + 34144512);              // 31,457,280 B
    const bool big  = ws_size >= (size_t)34144512;
    const bool bigx = ws_size >= (size_t)34144512 + 31457280;

    float* Xp = bigx ? xpws : (float*)d_out;

    hipMemsetAsync(flags, 0, 256, stream);

    if (big)
        cvt_bf16<<<8000, 256, 0, stream>>>(W_lin, wbf, 2048000);

    gemm_xproj<<<dim3(16, 30), 256, 0, stream>>>(
        feature, captions, embedding, W_ih, b_ih, b_hh, Xp);

    if (bigx) {
        // overlap path: LSTM + gemm_out consumers in ONE dispatch
        mega<<<dim3(LSTM_BLOCKS + 2500), 256, 0, stream>>>(
            Xp, W_hh, hbuf, dech, flags, wbf, b_lin, out);
    } else {
        // serial fallback (r7 pipeline): LSTM alone, then standalone GEMM2
        mega<<<dim3(LSTM_BLOCKS), 256, 0, stream>>>(
            Xp, W_hh, hbuf, dech, flags, (const short*)nullptr, b_lin, out);
        if (big)
            gemm_out<true><<<dim3(250, 10), 256, 0, stream>>>(
                (const short*)dech, wbf, b_lin, out, 1216, 32000, 512);
        else
            gemm_out<false><<<dim3(250, 10), 256, 0, stream>>>(
                (const short*)dech, W_lin, b_lin, out, 1216, 32000, 512);
    }
}

// Round 9
// 746.009 us; speedup vs baseline: 1.1849x; 1.1849x over previous
//
#include <hip/hip_runtime.h>
#include <hip/hip_bf16.h>

// B=64, T=60 (40 enc + 20 dec), H=512, E=512, V=32000. fp32 I/O.
// r9 structure:
//   1) prep (ONE dispatch): blocks 0..479 = gemm_xproj tiles (enc tiles skip
//      k<512 — x is zero there, exact); block 480 zeroes flags+epoch;
//      blocks 481..8480 = cvt W_lin fp32->bf16. Replaces 3 dispatches.
//   2) mega: blocks 0..31 persistent LSTM (r7 body + epoch publishes by
//      block 0); blocks 32..2531 gemm_out consumers, FIXED vs r8:
//        - 66KB shared -> 2 blocks/CU (r8: 144KB -> 1/CU, no hiding)
//        - no A-slab preload: A staged per-k0 (bypass u64 -> padded LDS)
//        - poll a single epoch cell (flags[32]) written only by LSTM block 0,
//          one lane per block, s_sleep(64) -> LSTM's flag line untouched
//   Fallback (small ws): mega grid=32 (LSTM only) + standalone gemm_out.

typedef short bf16x8 __attribute__((ext_vector_type(8)));
typedef float f32x4 __attribute__((ext_vector_type(4)));

__device__ inline short f2bf(float f) {
    unsigned u = __float_as_uint(f);
    unsigned r = (u + 0x7fffu + ((u >> 16) & 1u)) >> 16;   // RNE
    return (short)r;
}
__device__ inline int4 ld8_f32_to_bf16(const float* __restrict__ g) {
    float4 a = *(const float4*)g;
    float4 b = *(const float4*)(g + 4);
    union { short s[8]; int4 v; } u;
    u.s[0] = f2bf(a.x); u.s[1] = f2bf(a.y); u.s[2] = f2bf(a.z); u.s[3] = f2bf(a.w);
    u.s[4] = f2bf(b.x); u.s[5] = f2bf(b.y); u.s[6] = f2bf(b.z); u.s[7] = f2bf(b.w);
    return u.v;
}
__device__ inline float sig_fast(float x) {
    return __builtin_amdgcn_rcpf(1.0f + __expf(-x));
}
__device__ inline float tanh_fast(float x) {
    return 1.0f - 2.0f * __builtin_amdgcn_rcpf(1.0f + __expf(2.0f * x));
}
__device__ inline void gload_lds16(const void* g, void* l) {
    __builtin_amdgcn_global_load_lds(
        (const __attribute__((address_space(1))) void*)g,
        (__attribute__((address_space(3))) void*)l, 16, 0, 0);
}

#define LSTM_BLOCKS 32

// ---------------------------------------------------------------------------
// PREP: xproj tiles (0..479) | flags zero (480) | cvt (481..8480).
// ---------------------------------------------------------------------------
__global__ __launch_bounds__(256) void prep(
    const float* __restrict__ feature,    // [64][60][512]
    const int*   __restrict__ captions,   // [64][20]
    const float* __restrict__ embedding,  // [32000][512]
    const float* __restrict__ W_ih,       // [2048][1024]
    const float* __restrict__ b_ih,
    const float* __restrict__ b_hh,
    float* __restrict__ Xp,               // [3840][2048]
    const float* __restrict__ W_lin,      // [32000][512]
    short* __restrict__ wbf,              // bf16 dst or nullptr
    unsigned* __restrict__ flags)         // 64 dwords zeroed
{
    const int blk = blockIdx.x;
    const int tid = threadIdx.x;

    if (blk == 480) {
        if (tid < 64) flags[tid] = 0;
        return;
    }
    if (blk > 480) {
        if (wbf) {
            int i = (blk - 481) * 256 + tid;
            if (i < 2048000)
                *(int4*)&wbf[(size_t)i * 8] = ld8_f32_to_bf16(&W_lin[(size_t)i * 8]);
        }
        return;
    }

    // ----- xproj tile -----
    __shared__ __align__(16) short Al[128 * 72];
    __shared__ __align__(16) short Bl[128 * 72];
    const int wave = tid >> 6, lane = tid & 63;
    const int quad = lane >> 4, l16 = lane & 15;
    const int bx = blk & 15, by = blk >> 4;
    const int m0 = by * 128;
    const int n0 = bx * 128;
    const int wm = (wave >> 1) * 64, wn = (wave & 1) * 64;
    const int sr = tid >> 3;
    const int sc = (tid & 7) * 8;
    const bool dec = (by >= 20);          // rows t>=40 exactly when by>=20
    const int kstart = dec ? 0 : 512;     // enc rows: x[0..511]==0 -> skip

    f32x4 acc[4][4] = {};

    for (int k0 = kstart; k0 < 1024; k0 += 64) {
        const int j = k0 + sc;
#pragma unroll
        for (int p = 0; p < 4; ++p) {
            int r = sr + p * 32;
            int row = m0 + r;
            int t = row >> 6, b = row & 63;
            int4 val;
            if (dec && j < 512) {
                int tok = captions[b * 20 + (t - 40)];
                val = ld8_f32_to_bf16(&embedding[(size_t)tok * 512 + j]);
            } else {
                val = ld8_f32_to_bf16(&feature[(size_t)(b * 60 + t) * 512 + (j - 512)]);
            }
            *(int4*)&Al[r * 72 + sc] = val;
            *(int4*)&Bl[r * 72 + sc] = ld8_f32_to_bf16(&W_ih[(size_t)(n0 + r) * 1024 + j]);
        }
        __syncthreads();
#pragma unroll
        for (int kk = 0; kk < 64; kk += 32) {
            bf16x8 af[4], bg[4];
#pragma unroll
            for (int i = 0; i < 4; ++i)
                af[i] = *(const bf16x8*)&Al[(wm + i * 16 + l16) * 72 + kk + quad * 8];
#pragma unroll
            for (int jj = 0; jj < 4; ++jj)
                bg[jj] = *(const bf16x8*)&Bl[(wn + jj * 16 + l16) * 72 + kk + quad * 8];
#pragma unroll
            for (int i = 0; i < 4; ++i)
#pragma unroll
                for (int jj = 0; jj < 4; ++jj)
                    acc[i][jj] = __builtin_amdgcn_mfma_f32_16x16x32_bf16(
                        af[i], bg[jj], acc[i][jj], 0, 0, 0);
        }
        __syncthreads();
    }

#pragma unroll
    for (int jj = 0; jj < 4; ++jj) {
        int n = n0 + wn + jj * 16 + l16;
        float bv = b_ih[n] + b_hh[n];
#pragma unroll
        for (int i = 0; i < 4; ++i) {
            int mbase = m0 + wm + i * 16 + quad * 4;
#pragma unroll
            for (int r = 0; r < 4; ++r)
                Xp[(size_t)(mbase + r) * 2048 + n] = acc[i][jj][r] + bv;
        }
    }
}

// ---------------------------------------------------------------------------
// Standalone GEMM2 (serial fallback): A slice-major bf16; C rows permuted.
// ---------------------------------------------------------------------------
template <bool BF16B>
__global__ __launch_bounds__(256) void gemm_out(
    const short* __restrict__ A,
    const void*  __restrict__ Wv,
    const float* __restrict__ bias,
    float* __restrict__ C,
    int M, int N, int K)
{
    __shared__ __align__(16) short Al[128 * 72];
    __shared__ __align__(16) short Bl[128 * 72];
    const int tid  = threadIdx.x;
    const int wave = tid >> 6, lane = tid & 63;
    const int quad = lane >> 4, l16 = lane & 15;
    const int m0 = blockIdx.y * 128;
    const int n0 = blockIdx.x * 128;
    const int wm = (wave >> 1) * 64, wn = (wave & 1) * 64;
    const int sr = tid >> 3;
    const int sc = (tid & 7) * 8;

    f32x4 acc[4][4] = {};

    for (int k0 = 0; k0 < K; k0 += 64) {
        if (BF16B) {
            const char* Ab = (const char*)A;
            const char* Wb = (const char*)Wv;
            char* AlB = (char*)Al;
            char* BlB = (char*)Bl;
#pragma unroll
            for (int p = 0; p < 4; ++p) {
                int row = p * 32 + wave * 8 + (lane >> 3);
                int ss  = ((lane & 7) ^ (row & 7)) << 4;
                int am  = m0 + row; am = (am < M) ? am : (M - 1);
                gload_lds16(Ab + (size_t)am * 1024 + k0 * 2 + ss,
                            AlB + p * 4096 + wave * 1024);
                gload_lds16(Wb + (size_t)(n0 + row) * 1024 + k0 * 2 + ss,
                            BlB + p * 4096 + wave * 1024);
            }
        } else {
#pragma unroll
            for (int p = 0; p < 4; ++p) {
                int r = sr + p * 32;
                int am = m0 + r;
                am = (am < M) ? am : (M - 1);
                *(int4*)&Al[r * 72 + sc] = *(const int4*)&A[(size_t)am * K + k0 + sc];
                *(int4*)&Bl[r * 72 + sc] =
                    ld8_f32_to_bf16(&((const float*)Wv)[(size_t)(n0 + r) * K + k0 + sc]);
            }
        }
        __syncthreads();
#pragma unroll
        for (int kk = 0; kk < 64; kk += 32) {
            bf16x8 af[4], bg[4];
            if (BF16B) {
                const int s_ = (kk >> 3) + quad;
#pragma unroll
                for (int i = 0; i < 4; ++i) {
                    int rw = wm + i * 16 + l16;
                    af[i] = *(const bf16x8*)&Al[rw * 64 + ((s_ ^ (rw & 7)) << 3)];
                }
#pragma unroll
                for (int jj = 0; jj < 4; ++jj) {
                    int rw = wn + jj * 16 + l16;
                    bg[jj] = *(const bf16x8*)&Bl[rw * 64 + ((s_ ^ (rw & 7)) << 3)];
                }
            } else {
#pragma unroll
                for (int i = 0; i < 4; ++i)
                    af[i] = *(const bf16x8*)&Al[(wm + i * 16 + l16) * 72 + kk + quad * 8];
#pragma unroll
                for (int jj = 0; jj < 4; ++jj)
                    bg[jj] = *(const bf16x8*)&Bl[(wn + jj * 16 + l16) * 72 + kk + quad * 8];
            }
#pragma unroll
            for (int i = 0; i < 4; ++i)
#pragma unroll
                for (int jj = 0; jj < 4; ++jj)
                    acc[i][jj] = __builtin_amdgcn_mfma_f32_16x16x32_bf16(
                        af[i], bg[jj], acc[i][jj], 0, 0, 0);
        }
        __syncthreads();
    }

#pragma unroll
    for (int jj = 0; jj < 4; ++jj) {
        int n = n0 + wn + jj * 16 + l16;
        float bv = bias[n];
#pragma unroll
        for (int i = 0; i < 4; ++i) {
            int mbase = m0 + wm + i * 16 + quad * 4;
#pragma unroll
            for (int r = 0; r < 4; ++r) {
                int ar = mbase + r;
                if (ar < M) {
                    int crow = (ar & 63) * 19 + (ar >> 6);   // b*19 + dec
                    C[(size_t)crow * N + n] = acc[i][jj][r] + bv;
                }
            }
        }
    }
}

// ---------------------------------------------------------------------------
// MEGA: blocks 0..31 LSTM; blocks 32.. gemm_out consumers (v2, fixed).
// 66KB shared -> 2 blocks/CU everywhere.
// ---------------------------------------------------------------------------
__global__ __launch_bounds__(256, 1) void mega(
    const float* __restrict__ Xp,     // [59][64][2048] fp32
    const float* __restrict__ W_hh,   // [2048][512] fp32
    unsigned long long* __restrict__ hbuf,  // [2][64][512] bf16 ping-pong
    unsigned long long* __restrict__ dec_h, // [(t-40)*64+b][512] bf16 as u64
    unsigned* __restrict__ flags,     // [33]: 0..31 per-block, 32 = epoch
    const short* __restrict__ wbf,    // [32000][512] bf16
    const float* __restrict__ b_lin,  // [32000]
    float* __restrict__ out)          // [1216][32000] fp32
{
    __shared__ __align__(16) char smem[67584];   // 66 KB -> 2 blocks/CU
    const int tid  = threadIdx.x;
    const int wave = tid >> 6, lane = tid & 63;
    const int quad = lane >> 4, l16 = lane & 15;

    if (blockIdx.x < LSTM_BLOCKS) {
        // ================= LSTM (r7 body + epoch publishes) ================
        short* Wl  = (short*)smem;                 // 64 KB, swizzled
        short* Htb = (short*)(smem + 65536);       // 2 KB
        const int nb = blockIdx.x * 16;
        const int swz = (l16 & 7) << 3;

#pragma unroll
        for (int it = 0; it < 16; ++it) {
            int rr = (tid >> 6) + it * 4;
            int k  = (tid & 63) * 8;
            int s = rr >> 4, col = rr & 15;
            *(int4*)&Wl[(rr * 512 + k) ^ ((rr & 7) << 3)] =
                ld8_f32_to_bf16(&W_hh[(size_t)(s * 512 + nb + col) * 512 + k]);
        }
        float creg[4] = {0.f, 0.f, 0.f, 0.f};

        const int n = nb + l16;
        float xg[4][4];
#pragma unroll
        for (int r = 0; r < 4; ++r) {
            const float* xr = Xp + (size_t)(wave * 16 + quad * 4 + r) * 2048;
            xg[r][0] = xr[n];
            xg[r][1] = xr[512 + n];
            xg[r][2] = xr[1024 + n];
            xg[r][3] = xr[1536 + n];
        }
        __syncthreads();

        for (int t = 0; t < 59; ++t) {
            f32x4 acc[4] = {};
            if (t > 0) {
                const unsigned long long* hrow =
                    hbuf + ((size_t)((t & 1) ^ 1) << 13)
                         + (size_t)(wave * 16 + l16) * 128 + quad * 2;
                union { unsigned long long q[2]; bf16x8 v; } hu[16];
#pragma unroll
                for (int kk = 0; kk < 16; ++kk) {
                    hu[kk].q[0] = __hip_atomic_load(&hrow[kk * 8],
                                     __ATOMIC_RELAXED, __HIP_MEMORY_SCOPE_AGENT);
                    hu[kk].q[1] = __hip_atomic_load(&hrow[kk * 8 + 1],
                                     __ATOMIC_RELAXED, __HIP_MEMORY_SCOPE_AGENT);
                }
                __builtin_amdgcn_sched_barrier(0);
#pragma unroll
                for (int kk = 0; kk < 16; ++kk) {
#pragma unroll
                    for (int s = 0; s < 4; ++s) {
                        bf16x8 bg = *(const bf16x8*)
                            &Wl[((s * 16 + l16) * 512 + kk * 32 + quad * 8) ^ swz];
                        acc[s] = __builtin_amdgcn_mfma_f32_16x16x32_bf16(
                            hu[kk].v, bg, acc[s], 0, 0, 0);
                    }
                }
            }
#pragma unroll
            for (int r = 0; r < 4; ++r) {
                float iv = acc[0][r] + xg[r][0];
                float fv = acc[1][r] + xg[r][1];
                float gv = acc[2][r] + xg[r][2];
                float ov = acc[3][r] + xg[r][3];
                float cn = sig_fast(fv) * creg[r] + sig_fast(iv) * tanh_fast(gv);
                float hn = sig_fast(ov) * tanh_fast(cn);
                creg[r] = cn;
                Htb[(wave << 8) + ((quad * 4 + r) << 4) + l16] = f2bf(hn);
            }
            asm volatile("s_waitcnt lgkmcnt(0)" ::: "memory");
            unsigned long long* hout64 = hbuf + ((size_t)(t & 1) << 13);
            {
                int row = lane >> 2, qp = lane & 3;
                unsigned long long v =
                    *(const unsigned long long*)&Htb[(wave << 8) + (row << 4) + qp * 4];
                int m = wave * 16 + row;
                __hip_atomic_store(&hout64[m * 128 + (nb >> 2) + qp], v,
                                   __ATOMIC_RELAXED, __HIP_MEMORY_SCOPE_AGENT);
                if (t >= 40)
                    __hip_atomic_store(
                        &dec_h[(size_t)((t - 40) * 64 + m) * 128 + (nb >> 2) + qp], v,
                        __ATOMIC_RELAXED, __HIP_MEMORY_SCOPE_AGENT);
            }
            if (t < 58) {
                float xn_[4][4];
                const float* xt = Xp + (size_t)(t + 1) * 131072;
#pragma unroll
                for (int r = 0; r < 4; ++r) {
                    const float* xr = xt + (size_t)(wave * 16 + quad * 4 + r) * 2048;
                    xn_[r][0] = xr[n];
                    xn_[r][1] = xr[512 + n];
                    xn_[r][2] = xr[1024 + n];
                    xn_[r][3] = xr[1536 + n];
                }
                __syncthreads();   // drains vmcnt(0): h+dec_h at coherence pt
                if (tid == 0)
                    __hip_atomic_store(&flags[blockIdx.x], (unsigned)(t + 1),
                                       __ATOMIC_RELAXED, __HIP_MEMORY_SCOPE_AGENT);
                if (tid < LSTM_BLOCKS) {
                    int guard = 0;
                    while (__hip_atomic_load(&flags[tid], __ATOMIC_RELAXED,
                                             __HIP_MEMORY_SCOPE_AGENT) < (unsigned)(t + 1)
                           && guard < (1 << 16)) {
                        __builtin_amdgcn_s_sleep(1);
                        ++guard;
                    }
                }
                __syncthreads();
                // epoch: all flags >= t+1 observed -> consumers may read
                // slices <= t-40. Block 0 only; its own flag line untouched
                // by consumers.
                if (blockIdx.x == 0 && tid == 0)
                    __hip_atomic_store(&flags[32], (unsigned)(t + 1),
                                       __ATOMIC_RELAXED, __HIP_MEMORY_SCOPE_AGENT);
#pragma unroll
                for (int r = 0; r < 4; ++r)
#pragma unroll
                    for (int g = 0; g < 4; ++g)
                        xg[r][g] = xn_[r][g];
            }
        }
        // final publish: slice 18 (t=58) visible -> flag 59; block 0 raises
        // epoch to 59 after observing all flags.
        __syncthreads();           // drains t=58 dec_h/h stores
        if (tid == 0)
            __hip_atomic_store(&flags[blockIdx.x], 59u,
                               __ATOMIC_RELAXED, __HIP_MEMORY_SCOPE_AGENT);
        if (blockIdx.x == 0) {
            if (tid < LSTM_BLOCKS) {
                int guard = 0;
                while (__hip_atomic_load(&flags[tid], __ATOMIC_RELAXED,
                                         __HIP_MEMORY_SCOPE_AGENT) < 59u
                       && guard < (1 << 16)) {
                    __builtin_amdgcn_s_sleep(1);
                    ++guard;
                }
            }
            __syncthreads();
            if (tid == 0)
                __hip_atomic_store(&flags[32], 59u,
                                   __ATOMIC_RELAXED, __HIP_MEMORY_SCOPE_AGENT);
        }
        return;
    }

    // ================= consumer v2: one 128x128 tile of out ================
    short* Al = (short*)smem;                      // 128 x 72 padded (A)
    short* Bl = (short*)(smem + 18432);            // 128 x 64 swizzled (B)
    const int cid = blockIdx.x - LSTM_BLOCKS;
    const int n0 = (cid % 250) * 128;
    const int mt = cid / 250;
    const int m0 = mt * 128;
    const int M = 1216;
    const int wm = (wave >> 1) * 64, wn = (wave & 1) * 64;
    const int sr = tid >> 3;
    const int sc = (tid & 7) * 8;
    int maxa = m0 + 127; maxa = (maxa < M - 1) ? maxa : (M - 1);
    const unsigned v = 41u + (unsigned)(maxa >> 6);

    // single-lane poll of the epoch cell (coarse; does not touch flags 0..31)
    if (tid == 0) {
        int guard = 0;
        while (__hip_atomic_load(&flags[32], __ATOMIC_RELAXED,
                                 __HIP_MEMORY_SCOPE_AGENT) < v
               && guard < (1 << 14)) {
            __builtin_amdgcn_s_sleep(64);
            ++guard;
        }
    }
    __syncthreads();

    f32x4 acc[4][4] = {};
    const char* Wb = (const char*)wbf;
    char* BlB = (char*)Bl;

    for (int k0 = 0; k0 < 512; k0 += 64) {
        // A: per-k0 bypass u64 -> reg -> padded LDS (no preload slab)
#pragma unroll
        for (int p = 0; p < 4; ++p) {
            int r = sr + p * 32;
            int ar = m0 + r; ar = (ar < M) ? ar : (M - 1);
            size_t qi = (size_t)ar * 128 + ((k0 + sc) >> 2);
            union { unsigned long long q[2]; int4 v4; } u;
            u.q[0] = __hip_atomic_load(&dec_h[qi],
                         __ATOMIC_RELAXED, __HIP_MEMORY_SCOPE_AGENT);
            u.q[1] = __hip_atomic_load(&dec_h[qi + 1],
                         __ATOMIC_RELAXED, __HIP_MEMORY_SCOPE_AGENT);
            *(int4*)&Al[r * 72 + sc] = u.v4;
        }
        // B: swizzled global_load_lds (r7-proven)
#pragma unroll
        for (int p = 0; p < 4; ++p) {
            int row = p * 32 + wave * 8 + (lane >> 3);
            int ss  = ((lane & 7) ^ (row & 7)) << 4;
            gload_lds16(Wb + (size_t)(n0 + row) * 1024 + k0 * 2 + ss,
                        BlB + p * 4096 + wave * 1024);
        }
        __syncthreads();
#pragma unroll
        for (int kk = 0; kk < 64; kk += 32) {
            bf16x8 af[4], bg[4];
            const int s_ = (kk >> 3) + quad;
#pragma unroll
            for (int i = 0; i < 4; ++i)
                af[i] = *(const bf16x8*)&Al[(wm + i * 16 + l16) * 72 + kk + quad * 8];
#pragma unroll
            for (int jj = 0; jj < 4; ++jj) {
                int rw = wn + jj * 16 + l16;
                bg[jj] = *(const bf16x8*)&Bl[rw * 64 + ((s_ ^ (rw & 7)) << 3)];
            }
#pragma unroll
            for (int i = 0; i < 4; ++i)
#pragma unroll
                for (int jj = 0; jj < 4; ++jj)
                    acc[i][jj] = __builtin_amdgcn_mfma_f32_16x16x32_bf16(
                        af[i], bg[jj], acc[i][jj], 0, 0, 0);
        }
        __syncthreads();
    }

#pragma unroll
    for (int jj = 0; jj < 4; ++jj) {
        int n = n0 + wn + jj * 16 + l16;
        float bv = b_lin[n];
#pragma unroll
        for (int i = 0; i < 4; ++i) {
            int mbase = m0 + wm + i * 16 + quad * 4;
#pragma unroll
            for (int r = 0; r < 4; ++r) {
                int ar = mbase + r;
                if (ar < M) {
                    int crow = (ar & 63) * 19 + (ar >> 6);   // b*19 + dec
                    out[(size_t)crow * 32000 + n] = acc[i][jj][r] + bv;
                }
            }
        }
    }
}

// ---------------------------------------------------------------------------
extern "C" void kernel_launch(void* const* d_in, const int* in_sizes, int n_in,
                              void* d_out, int out_size, void* d_ws, size_t ws_size,
                              hipStream_t stream)
{
    (void)in_sizes; (void)n_in; (void)out_size;
    const float* feature   = (const float*)d_in[0];
    const int*   captions  = (const int*)d_in[1];
    const float* embedding = (const float*)d_in[2];
    const float* W_ih      = (const float*)d_in[3];
    const float* W_hh      = (const float*)d_in[4];
    const float* b_ih      = (const float*)d_in[5];
    const float* b_hh      = (const float*)d_in[6];
    const float* W_lin     = (const float*)d_in[7];
    const float* b_lin     = (const float*)d_in[8];
    float* out = (float*)d_out;

    // ws layout
    char* ws = (char*)d_ws;
    unsigned long long* hbuf = (unsigned long long*)(ws);          // 131,072 B
    unsigned long long* dech = (unsigned long long*)(ws + 131072); // 1,245,184 B
    unsigned* flags = (unsigned*)(ws + 1376256);                   // 256 B
    short*    wbf   = (short*)(ws + 1376512);                      // 32,768,000 B
    float*    xpws  = (float*)(ws + 34144512);                     // 31,457,280 B
    const bool big  = ws_size >= (size_t)34144512;
    const bool bigx = ws_size >= (size_t)34144512 + 31457280;

    float* Xp = bigx ? xpws : (float*)d_out;

    // prep: xproj + flags-zero + (cvt if big). Replaces memset+cvt+xproj.
    prep<<<dim3(big ? 8481 : 481), 256, 0, stream>>>(
        feature, captions, embedding, W_ih, b_ih, b_hh, Xp,
        W_lin, big ? wbf : (short*)nullptr, flags);

    if (bigx) {
        // overlap path: LSTM + gemm_out consumers in ONE dispatch
        mega<<<dim3(LSTM_BLOCKS + 2500), 256, 0, stream>>>(
            Xp, W_hh, hbuf, dech, flags, wbf, b_lin, out);
    } else {
        // serial fallback: LSTM alone, then standalone GEMM2
        mega<<<dim3(LSTM_BLOCKS), 256, 0, stream>>>(
            Xp, W_hh, hbuf, dech, flags, (const short*)nullptr, b_lin, out);
        if (big)
            gemm_out<true><<<dim3(250, 10), 256, 0, stream>>>(
                (const short*)dech, wbf, b_lin, out, 1216, 32000, 512);
        else
            gemm_out<false><<<dim3(250, 10), 256, 0, stream>>>(
                (const short*)dech, W_lin, b_lin, out, 1216, 32000, 512);
    }
}

// Round 10
// 674.655 us; speedup vs baseline: 1.3102x; 1.1058x over previous
//
#include <hip/hip_runtime.h>
#include <hip/hip_bf16.h>

// B=64, T=60 (40 enc + 20 dec), H=512, E=512, V=32000. fp32 I/O.
// r10 structure (overlap path, ws >= 65.6MB):
//   1) prep_new (2048 blocks, grid-stride streaming): builds xs[3840][1024]
//      bf16 (cols 512..1023 = feature for all rows; cols 0..511 = embedding
//      gather for dec rows only — enc region left unwritten, never read),
//      cvt W_ih -> wih bf16, cvt W_lin -> wbf bf16, zeroes flags.
//      xs/wih live in d_out's TAIL (dead before mega's consumers write out).
//   2) xproj_gemm: PURE-bf16 GEMM (r7-proven swizzled global_load_lds
//      staging): Xp = xs @ wih^T + (b_ih+b_hh); enc m-tiles start K at 512.
//      Replaces old xproj whose in-loop captions->embedding->cvt dependent
//      chain measured ~270us (~55 TF).
//   3) mega (unchanged from r9, measured 420us): blocks 0..31 persistent
//      LSTM; blocks 32..2531 gemm_out consumers (66KB LDS -> 2/CU, per-k0
//      A staging, single epoch cell poll).
//   Fallback (ws < 65.6MB): r9's prep_old + mega(grid=32) + gemm_out.

typedef short bf16x8 __attribute__((ext_vector_type(8)));
typedef float f32x4 __attribute__((ext_vector_type(4)));

__device__ inline short f2bf(float f) {
    unsigned u = __float_as_uint(f);
    unsigned r = (u + 0x7fffu + ((u >> 16) & 1u)) >> 16;   // RNE
    return (short)r;
}
__device__ inline int4 ld8_f32_to_bf16(const float* __restrict__ g) {
    float4 a = *(const float4*)g;
    float4 b = *(const float4*)(g + 4);
    union { short s[8]; int4 v; } u;
    u.s[0] = f2bf(a.x); u.s[1] = f2bf(a.y); u.s[2] = f2bf(a.z); u.s[3] = f2bf(a.w);
    u.s[4] = f2bf(b.x); u.s[5] = f2bf(b.y); u.s[6] = f2bf(b.z); u.s[7] = f2bf(b.w);
    return u.v;
}
__device__ inline float sig_fast(float x) {
    return __builtin_amdgcn_rcpf(1.0f + __expf(-x));
}
__device__ inline float tanh_fast(float x) {
    return 1.0f - 2.0f * __builtin_amdgcn_rcpf(1.0f + __expf(2.0f * x));
}
__device__ inline void gload_lds16(const void* g, void* l) {
    __builtin_amdgcn_global_load_lds(
        (const __attribute__((address_space(1))) void*)g,
        (__attribute__((address_space(3))) void*)l, 16, 0, 0);
}

#define LSTM_BLOCKS 32

// ---------------------------------------------------------------------------
// prep_new: streaming build/convert pass (no LDS, grid-stride).
//   section A: xs feature cols  (NF = 3840*64 chunks of 8)
//   section B: xs embedding gather for dec rows (NE = 1280*64)
//   section C: W_ih cvt (NW = 2048*128)
//   section D: W_lin cvt (NL = 2048000)
//   block 0: zero flags
// ---------------------------------------------------------------------------
__global__ __launch_bounds__(256) void prep_new(
    const float* __restrict__ feature,    // [64][60][512]
    const int*   __restrict__ captions,   // [64][20]
    const float* __restrict__ embedding,  // [32000][512]
    const float* __restrict__ W_ih,       // [2048][1024]
    const float* __restrict__ W_lin,      // [32000][512]
    short* __restrict__ xs,               // [3840][1024] bf16
    short* __restrict__ wih,              // [2048][1024] bf16
    short* __restrict__ wbf,              // [32000][512] bf16
    unsigned* __restrict__ flags)
{
    const int tid = threadIdx.x;
    if (blockIdx.x == 0 && tid < 64) flags[tid] = 0;

    const int NF = 3840 * 64;
    const int NE = 1280 * 64;
    const int NW = 2048 * 128;
    const int NL = 2048000;
    const int total = NF + NE + NW + NL;
    const int stride = gridDim.x * 256;

    for (int idx = blockIdx.x * 256 + tid; idx < total; idx += stride) {
        if (idx < NF) {
            int row = idx >> 6, c8 = (idx & 63) * 8;      // row 0..3839
            int t = row >> 6, b = row & 63;
            *(int4*)&xs[(size_t)row * 1024 + 512 + c8] =
                ld8_f32_to_bf16(&feature[(size_t)(b * 60 + t) * 512 + c8]);
        } else if (idx < NF + NE) {
            int j = idx - NF;
            int r = j >> 6, c8 = (j & 63) * 8;            // r 0..1279
            int t = 40 + (r >> 6), b = r & 63;
            int tok = captions[b * 20 + (t - 40)];
            *(int4*)&xs[(size_t)(2560 + r) * 1024 + c8] =
                ld8_f32_to_bf16(&embedding[(size_t)tok * 512 + c8]);
        } else if (idx < NF + NE + NW) {
            int j = idx - NF - NE;
            *(int4*)&wih[(size_t)j * 8] = ld8_f32_to_bf16(&W_ih[(size_t)j * 8]);
        } else {
            int j = idx - NF - NE - NW;
            *(int4*)&wbf[(size_t)j * 8] = ld8_f32_to_bf16(&W_lin[(size_t)j * 8]);
        }
    }
}

// ---------------------------------------------------------------------------
// xproj_gemm: Xp[3840][2048] = xs @ wih^T + (b_ih+b_hh), pure bf16 inputs,
// swizzled global_load_lds staging (r7-proven). Enc m-tiles (by<20) start K
// at 512 (xs cols 0..511 are unwritten for enc rows — never read).
// ---------------------------------------------------------------------------
__global__ __launch_bounds__(256) void xproj_gemm(
    const short* __restrict__ xs,     // [3840][1024] bf16
    const short* __restrict__ wih,    // [2048][1024] bf16
    const float* __restrict__ b_ih,
    const float* __restrict__ b_hh,
    float* __restrict__ Xp)           // [3840][2048]
{
    __shared__ __align__(16) short Al[128 * 64];
    __shared__ __align__(16) short Bl[128 * 64];
    const int tid  = threadIdx.x;
    const int wave = tid >> 6, lane = tid & 63;
    const int quad = lane >> 4, l16 = lane & 15;
    const int m0 = blockIdx.y * 128;
    const int n0 = blockIdx.x * 128;
    const int wm = (wave >> 1) * 64, wn = (wave & 1) * 64;
    const int kstart = (blockIdx.y >= 20) ? 0 : 512;   // enc rows: x[:512]==0

    const char* Ab = (const char*)xs;     // row stride 2048 B
    const char* Wb = (const char*)wih;    // row stride 2048 B
    char* AlB = (char*)Al;
    char* BlB = (char*)Bl;

    f32x4 acc[4][4] = {};

    for (int k0 = kstart; k0 < 1024; k0 += 64) {
#pragma unroll
        for (int p = 0; p < 4; ++p) {
            int row = p * 32 + wave * 8 + (lane >> 3);   // 0..127
            int ss  = ((lane & 7) ^ (row & 7)) << 4;     // swizzled 16B slot
            gload_lds16(Ab + (size_t)(m0 + row) * 2048 + k0 * 2 + ss,
                        AlB + p * 4096 + wave * 1024);
            gload_lds16(Wb + (size_t)(n0 + row) * 2048 + k0 * 2 + ss,
                        BlB + p * 4096 + wave * 1024);
        }
        __syncthreads();
#pragma unroll
        for (int kk = 0; kk < 64; kk += 32) {
            bf16x8 af[4], bg[4];
            const int s_ = (kk >> 3) + quad;
#pragma unroll
            for (int i = 0; i < 4; ++i) {
                int rw = wm + i * 16 + l16;
                af[i] = *(const bf16x8*)&Al[rw * 64 + ((s_ ^ (rw & 7)) << 3)];
            }
#pragma unroll
            for (int jj = 0; jj < 4; ++jj) {
                int rw = wn + jj * 16 + l16;
                bg[jj] = *(const bf16x8*)&Bl[rw * 64 + ((s_ ^ (rw & 7)) << 3)];
            }
#pragma unroll
            for (int i = 0; i < 4; ++i)
#pragma unroll
                for (int jj = 0; jj < 4; ++jj)
                    acc[i][jj] = __builtin_amdgcn_mfma_f32_16x16x32_bf16(
                        af[i], bg[jj], acc[i][jj], 0, 0, 0);
        }
        __syncthreads();
    }

#pragma unroll
    for (int jj = 0; jj < 4; ++jj) {
        int n = n0 + wn + jj * 16 + l16;
        float bv = b_ih[n] + b_hh[n];
#pragma unroll
        for (int i = 0; i < 4; ++i) {
            int mbase = m0 + wm + i * 16 + quad * 4;
#pragma unroll
            for (int r = 0; r < 4; ++r)
                Xp[(size_t)(mbase + r) * 2048 + n] = acc[i][jj][r] + bv;
        }
    }
}

// ---------------------------------------------------------------------------
// prep_old (fallback path only — verbatim r9): xproj tiles | flags | cvt.
// ---------------------------------------------------------------------------
__global__ __launch_bounds__(256) void prep_old(
    const float* __restrict__ feature,
    const int*   __restrict__ captions,
    const float* __restrict__ embedding,
    const float* __restrict__ W_ih,
    const float* __restrict__ b_ih,
    const float* __restrict__ b_hh,
    float* __restrict__ Xp,
    const float* __restrict__ W_lin,
    short* __restrict__ wbf,
    unsigned* __restrict__ flags)
{
    const int blk = blockIdx.x;
    const int tid = threadIdx.x;

    if (blk == 480) {
        if (tid < 64) flags[tid] = 0;
        return;
    }
    if (blk > 480) {
        if (wbf) {
            int i = (blk - 481) * 256 + tid;
            if (i < 2048000)
                *(int4*)&wbf[(size_t)i * 8] = ld8_f32_to_bf16(&W_lin[(size_t)i * 8]);
        }
        return;
    }

    __shared__ __align__(16) short Al[128 * 72];
    __shared__ __align__(16) short Bl[128 * 72];
    const int wave = tid >> 6, lane = tid & 63;
    const int quad = lane >> 4, l16 = lane & 15;
    const int bx = blk & 15, by = blk >> 4;
    const int m0 = by * 128;
    const int n0 = bx * 128;
    const int wm = (wave >> 1) * 64, wn = (wave & 1) * 64;
    const int sr = tid >> 3;
    const int sc = (tid & 7) * 8;
    const bool dec = (by >= 20);
    const int kstart = dec ? 0 : 512;

    f32x4 acc[4][4] = {};

    for (int k0 = kstart; k0 < 1024; k0 += 64) {
        const int j = k0 + sc;
#pragma unroll
        for (int p = 0; p < 4; ++p) {
            int r = sr + p * 32;
            int row = m0 + r;
            int t = row >> 6, b = row & 63;
            int4 val;
            if (dec && j < 512) {
                int tok = captions[b * 20 + (t - 40)];
                val = ld8_f32_to_bf16(&embedding[(size_t)tok * 512 + j]);
            } else {
                val = ld8_f32_to_bf16(&feature[(size_t)(b * 60 + t) * 512 + (j - 512)]);
            }
            *(int4*)&Al[r * 72 + sc] = val;
            *(int4*)&Bl[r * 72 + sc] = ld8_f32_to_bf16(&W_ih[(size_t)(n0 + r) * 1024 + j]);
        }
        __syncthreads();
#pragma unroll
        for (int kk = 0; kk < 64; kk += 32) {
            bf16x8 af[4], bg[4];
#pragma unroll
            for (int i = 0; i < 4; ++i)
                af[i] = *(const bf16x8*)&Al[(wm + i * 16 + l16) * 72 + kk + quad * 8];
#pragma unroll
            for (int jj = 0; jj < 4; ++jj)
                bg[jj] = *(const bf16x8*)&Bl[(wn + jj * 16 + l16) * 72 + kk + quad * 8];
#pragma unroll
            for (int i = 0; i < 4; ++i)
#pragma unroll
                for (int jj = 0; jj < 4; ++jj)
                    acc[i][jj] = __builtin_amdgcn_mfma_f32_16x16x32_bf16(
                        af[i], bg[jj], acc[i][jj], 0, 0, 0);
        }
        __syncthreads();
    }

#pragma unroll
    for (int jj = 0; jj < 4; ++jj) {
        int n = n0 + wn + jj * 16 + l16;
        float bv = b_ih[n] + b_hh[n];
#pragma unroll
        for (int i = 0; i < 4; ++i) {
            int mbase = m0 + wm + i * 16 + quad * 4;
#pragma unroll
            for (int r = 0; r < 4; ++r)
                Xp[(size_t)(mbase + r) * 2048 + n] = acc[i][jj][r] + bv;
        }
    }
}

// ---------------------------------------------------------------------------
// Standalone GEMM2 (serial fallback): A slice-major bf16; C rows permuted.
// ---------------------------------------------------------------------------
template <bool BF16B>
__global__ __launch_bounds__(256) void gemm_out(
    const short* __restrict__ A,
    const void*  __restrict__ Wv,
    const float* __restrict__ bias,
    float* __restrict__ C,
    int M, int N, int K)
{
    __shared__ __align__(16) short Al[128 * 72];
    __shared__ __align__(16) short Bl[128 * 72];
    const int tid  = threadIdx.x;
    const int wave = tid >> 6, lane = tid & 63;
    const int quad = lane >> 4, l16 = lane & 15;
    const int m0 = blockIdx.y * 128;
    const int n0 = blockIdx.x * 128;
    const int wm = (wave >> 1) * 64, wn = (wave & 1) * 64;
    const int sr = tid >> 3;
    const int sc = (tid & 7) * 8;

    f32x4 acc[4][4] = {};

    for (int k0 = 0; k0 < K; k0 += 64) {
        if (BF16B) {
            const char* Ab = (const char*)A;
            const char* Wb = (const char*)Wv;
            char* AlB = (char*)Al;
            char* BlB = (char*)Bl;
#pragma unroll
            for (int p = 0; p < 4; ++p) {
                int row = p * 32 + wave * 8 + (lane >> 3);
                int ss  = ((lane & 7) ^ (row & 7)) << 4;
                int am  = m0 + row; am = (am < M) ? am : (M - 1);
                gload_lds16(Ab + (size_t)am * 1024 + k0 * 2 + ss,
                            AlB + p * 4096 + wave * 1024);
                gload_lds16(Wb + (size_t)(n0 + row) * 1024 + k0 * 2 + ss,
                            BlB + p * 4096 + wave * 1024);
            }
        } else {
#pragma unroll
            for (int p = 0; p < 4; ++p) {
                int r = sr + p * 32;
                int am = m0 + r;
                am = (am < M) ? am : (M - 1);
                *(int4*)&Al[r * 72 + sc] = *(const int4*)&A[(size_t)am * K + k0 + sc];
                *(int4*)&Bl[r * 72 + sc] =
                    ld8_f32_to_bf16(&((const float*)Wv)[(size_t)(n0 + r) * K + k0 + sc]);
            }
        }
        __syncthreads();
#pragma unroll
        for (int kk = 0; kk < 64; kk += 32) {
            bf16x8 af[4], bg[4];
            if (BF16B) {
                const int s_ = (kk >> 3) + quad;
#pragma unroll
                for (int i = 0; i < 4; ++i) {
                    int rw = wm + i * 16 + l16;
                    af[i] = *(const bf16x8*)&Al[rw * 64 + ((s_ ^ (rw & 7)) << 3)];
                }
#pragma unroll
                for (int jj = 0; jj < 4; ++jj) {
                    int rw = wn + jj * 16 + l16;
                    bg[jj] = *(const bf16x8*)&Bl[rw * 64 + ((s_ ^ (rw & 7)) << 3)];
                }
            } else {
#pragma unroll
                for (int i = 0; i < 4; ++i)
                    af[i] = *(const bf16x8*)&Al[(wm + i * 16 + l16) * 72 + kk + quad * 8];
#pragma unroll
                for (int jj = 0; jj < 4; ++jj)
                    bg[jj] = *(const bf16x8*)&Bl[(wn + jj * 16 + l16) * 72 + kk + quad * 8];
            }
#pragma unroll
            for (int i = 0; i < 4; ++i)
#pragma unroll
                for (int jj = 0; jj < 4; ++jj)
                    acc[i][jj] = __builtin_amdgcn_mfma_f32_16x16x32_bf16(
                        af[i], bg[jj], acc[i][jj], 0, 0, 0);
        }
        __syncthreads();
    }

#pragma unroll
    for (int jj = 0; jj < 4; ++jj) {
        int n = n0 + wn + jj * 16 + l16;
        float bv = bias[n];
#pragma unroll
        for (int i = 0; i < 4; ++i) {
            int mbase = m0 + wm + i * 16 + quad * 4;
#pragma unroll
            for (int r = 0; r < 4; ++r) {
                int ar = mbase + r;
                if (ar < M) {
                    int crow = (ar & 63) * 19 + (ar >> 6);   // b*19 + dec
                    C[(size_t)crow * N + n] = acc[i][jj][r] + bv;
                }
            }
        }
    }
}

// ---------------------------------------------------------------------------
// MEGA (verbatim r9, measured 420us): blocks 0..31 LSTM; 32.. consumers.
// ---------------------------------------------------------------------------
__global__ __launch_bounds__(256, 1) void mega(
    const float* __restrict__ Xp,     // [59][64][2048] fp32
    const float* __restrict__ W_hh,   // [2048][512] fp32
    unsigned long long* __restrict__ hbuf,  // [2][64][512] bf16 ping-pong
    unsigned long long* __restrict__ dec_h, // [(t-40)*64+b][512] bf16 as u64
    unsigned* __restrict__ flags,     // [33]: 0..31 per-block, 32 = epoch
    const short* __restrict__ wbf,    // [32000][512] bf16
    const float* __restrict__ b_lin,  // [32000]
    float* __restrict__ out)          // [1216][32000] fp32
{
    __shared__ __align__(16) char smem[67584];   // 66 KB -> 2 blocks/CU
    const int tid  = threadIdx.x;
    const int wave = tid >> 6, lane = tid & 63;
    const int quad = lane >> 4, l16 = lane & 15;

    if (blockIdx.x < LSTM_BLOCKS) {
        short* Wl  = (short*)smem;                 // 64 KB, swizzled
        short* Htb = (short*)(smem + 65536);       // 2 KB
        const int nb = blockIdx.x * 16;
        const int swz = (l16 & 7) << 3;

#pragma unroll
        for (int it = 0; it < 16; ++it) {
            int rr = (tid >> 6) + it * 4;
            int k  = (tid & 63) * 8;
            int s = rr >> 4, col = rr & 15;
            *(int4*)&Wl[(rr * 512 + k) ^ ((rr & 7) << 3)] =
                ld8_f32_to_bf16(&W_hh[(size_t)(s * 512 + nb + col) * 512 + k]);
        }
        float creg[4] = {0.f, 0.f, 0.f, 0.f};

        const int n = nb + l16;
        float xg[4][4];
#pragma unroll
        for (int r = 0; r < 4; ++r) {
            const float* xr = Xp + (size_t)(wave * 16 + quad * 4 + r) * 2048;
            xg[r][0] = xr[n];
            xg[r][1] = xr[512 + n];
            xg[r][2] = xr[1024 + n];
            xg[r][3] = xr[1536 + n];
        }
        __syncthreads();

        for (int t = 0; t < 59; ++t) {
            f32x4 acc[4] = {};
            if (t > 0) {
                const unsigned long long* hrow =
                    hbuf + ((size_t)((t & 1) ^ 1) << 13)
                         + (size_t)(wave * 16 + l16) * 128 + quad * 2;
                union { unsigned long long q[2]; bf16x8 v; } hu[16];
#pragma unroll
                for (int kk = 0; kk < 16; ++kk) {
                    hu[kk].q[0] = __hip_atomic_load(&hrow[kk * 8],
                                     __ATOMIC_RELAXED, __HIP_MEMORY_SCOPE_AGENT);
                    hu[kk].q[1] = __hip_atomic_load(&hrow[kk * 8 + 1],
                                     __ATOMIC_RELAXED, __HIP_MEMORY_SCOPE_AGENT);
                }
                __builtin_amdgcn_sched_barrier(0);
#pragma unroll
                for (int kk = 0; kk < 16; ++kk) {
#pragma unroll
                    for (int s = 0; s < 4; ++s) {
                        bf16x8 bg = *(const bf16x8*)
                            &Wl[((s * 16 + l16) * 512 + kk * 32 + quad * 8) ^ swz];
                        acc[s] = __builtin_amdgcn_mfma_f32_16x16x32_bf16(
                            hu[kk].v, bg, acc[s], 0, 0, 0);
                    }
                }
            }
#pragma unroll
            for (int r = 0; r < 4; ++r) {
                float iv = acc[0][r] + xg[r][0];
                float fv = acc[1][r] + xg[r][1];
                float gv = acc[2][r] + xg[r][2];
                float ov = acc[3][r] + xg[r][3];
                float cn = sig_fast(fv) * creg[r] + sig_fast(iv) * tanh_fast(gv);
                float hn = sig_fast(ov) * tanh_fast(cn);
                creg[r] = cn;
                Htb[(wave << 8) + ((quad * 4 + r) << 4) + l16] = f2bf(hn);
            }
            asm volatile("s_waitcnt lgkmcnt(0)" ::: "memory");
            unsigned long long* hout64 = hbuf + ((size_t)(t & 1) << 13);
            {
                int row = lane >> 2, qp = lane & 3;
                unsigned long long v =
                    *(const unsigned long long*)&Htb[(wave << 8) + (row << 4) + qp * 4];
                int m = wave * 16 + row;
                __hip_atomic_store(&hout64[m * 128 + (nb >> 2) + qp], v,
                                   __ATOMIC_RELAXED, __HIP_MEMORY_SCOPE_AGENT);
                if (t >= 40)
                    __hip_atomic_store(
                        &dec_h[(size_t)((t - 40) * 64 + m) * 128 + (nb >> 2) + qp], v,
                        __ATOMIC_RELAXED, __HIP_MEMORY_SCOPE_AGENT);
            }
            if (t < 58) {
                float xn_[4][4];
                const float* xt = Xp + (size_t)(t + 1) * 131072;
#pragma unroll
                for (int r = 0; r < 4; ++r) {
                    const float* xr = xt + (size_t)(wave * 16 + quad * 4 + r) * 2048;
                    xn_[r][0] = xr[n];
                    xn_[r][1] = xr[512 + n];
                    xn_[r][2] = xr[1024 + n];
                    xn_[r][3] = xr[1536 + n];
                }
                __syncthreads();   // drains vmcnt(0): h+dec_h at coherence pt
                if (tid == 0)
                    __hip_atomic_store(&flags[blockIdx.x], (unsigned)(t + 1),
                                       __ATOMIC_RELAXED, __HIP_MEMORY_SCOPE_AGENT);
                if (tid < LSTM_BLOCKS) {
                    int guard = 0;
                    while (__hip_atomic_load(&flags[tid], __ATOMIC_RELAXED,
                                             __HIP_MEMORY_SCOPE_AGENT) < (unsigned)(t + 1)
                           && guard < (1 << 16)) {
                        __builtin_amdgcn_s_sleep(1);
                        ++guard;
                    }
                }
                __syncthreads();
                if (blockIdx.x == 0 && tid == 0)
                    __hip_atomic_store(&flags[32], (unsigned)(t + 1),
                                       __ATOMIC_RELAXED, __HIP_MEMORY_SCOPE_AGENT);
#pragma unroll
                for (int r = 0; r < 4; ++r)
#pragma unroll
                    for (int g = 0; g < 4; ++g)
                        xg[r][g] = xn_[r][g];
            }
        }
        __syncthreads();           // drains t=58 dec_h/h stores
        if (tid == 0)
            __hip_atomic_store(&flags[blockIdx.x], 59u,
                               __ATOMIC_RELAXED, __HIP_MEMORY_SCOPE_AGENT);
        if (blockIdx.x == 0) {
            if (tid < LSTM_BLOCKS) {
                int guard = 0;
                while (__hip_atomic_load(&flags[tid], __ATOMIC_RELAXED,
                                         __HIP_MEMORY_SCOPE_AGENT) < 59u
                       && guard < (1 << 16)) {
                    __builtin_amdgcn_s_sleep(1);
                    ++guard;
                }
            }
            __syncthreads();
            if (tid == 0)
                __hip_atomic_store(&flags[32], 59u,
                                   __ATOMIC_RELAXED, __HIP_MEMORY_SCOPE_AGENT);
        }
        return;
    }

    // ================= consumer v2: one 128x128 tile of out ================
    short* Al = (short*)smem;                      // 128 x 72 padded (A)
    short* Bl = (short*)(smem + 18432);            // 128 x 64 swizzled (B)
    const int cid = blockIdx.x - LSTM_BLOCKS;
    const int n0 = (cid % 250) * 128;
    const int mt = cid / 250;
    const int m0 = mt * 128;
    const int M = 1216;
    const int wm = (wave >> 1) * 64, wn = (wave & 1) * 64;
    const int sr = tid >> 3;
    const int sc = (tid & 7) * 8;
    int maxa = m0 + 127; maxa = (maxa < M - 1) ? maxa : (M - 1);
    const unsigned v = 41u + (unsigned)(maxa >> 6);

    if (tid == 0) {
        int guard = 0;
        while (__hip_atomic_load(&flags[32], __ATOMIC_RELAXED,
                                 __HIP_MEMORY_SCOPE_AGENT) < v
               && guard < (1 << 14)) {
            __builtin_amdgcn_s_sleep(64);
            ++guard;
        }
    }
    __syncthreads();

    f32x4 acc[4][4] = {};
    const char* Wb = (const char*)wbf;
    char* BlB = (char*)Bl;

    for (int k0 = 0; k0 < 512; k0 += 64) {
#pragma unroll
        for (int p = 0; p < 4; ++p) {
            int r = sr + p * 32;
            int ar = m0 + r; ar = (ar < M) ? ar : (M - 1);
            size_t qi = (size_t)ar * 128 + ((k0 + sc) >> 2);
            union { unsigned long long q[2]; int4 v4; } u;
            u.q[0] = __hip_atomic_load(&dec_h[qi],
                         __ATOMIC_RELAXED, __HIP_MEMORY_SCOPE_AGENT);
            u.q[1] = __hip_atomic_load(&dec_h[qi + 1],
                         __ATOMIC_RELAXED, __HIP_MEMORY_SCOPE_AGENT);
            *(int4*)&Al[r * 72 + sc] = u.v4;
        }
#pragma unroll
        for (int p = 0; p < 4; ++p) {
            int row = p * 32 + wave * 8 + (lane >> 3);
            int ss  = ((lane & 7) ^ (row & 7)) << 4;
            gload_lds16(Wb + (size_t)(n0 + row) * 1024 + k0 * 2 + ss,
                        BlB + p * 4096 + wave * 1024);
        }
        __syncthreads();
#pragma unroll
        for (int kk = 0; kk < 64; kk += 32) {
            bf16x8 af[4], bg[4];
            const int s_ = (kk >> 3) + quad;
#pragma unroll
            for (int i = 0; i < 4; ++i)
                af[i] = *(const bf16x8*)&Al[(wm + i * 16 + l16) * 72 + kk + quad * 8];
#pragma unroll
            for (int jj = 0; jj < 4; ++jj) {
                int rw = wn + jj * 16 + l16;
                bg[jj] = *(const bf16x8*)&Bl[rw * 64 + ((s_ ^ (rw & 7)) << 3)];
            }
#pragma unroll
            for (int i = 0; i < 4; ++i)
#pragma unroll
                for (int jj = 0; jj < 4; ++jj)
                    acc[i][jj] = __builtin_amdgcn_mfma_f32_16x16x32_bf16(
                        af[i], bg[jj], acc[i][jj], 0, 0, 0);
        }
        __syncthreads();
    }

#pragma unroll
    for (int jj = 0; jj < 4; ++jj) {
        int n = n0 + wn + jj * 16 + l16;
        float bv = b_lin[n];
#pragma unroll
        for (int i = 0; i < 4; ++i) {
            int mbase = m0 + wm + i * 16 + quad * 4;
#pragma unroll
            for (int r = 0; r < 4; ++r) {
                int ar = mbase + r;
                if (ar < M) {
                    int crow = (ar & 63) * 19 + (ar >> 6);   // b*19 + dec
                    out[(size_t)crow * 32000 + n] = acc[i][jj][r] + bv;
                }
            }
        }
    }
}

// ---------------------------------------------------------------------------
extern "C" void kernel_launch(void* const* d_in, const int* in_sizes, int n_in,
                              void* d_out, int out_size, void* d_ws, size_t ws_size,
                              hipStream_t stream)
{
    (void)in_sizes; (void)n_in; (void)out_size;
    const float* feature   = (const float*)d_in[0];
    const int*   captions  = (const int*)d_in[1];
    const float* embedding = (const float*)d_in[2];
    const float* W_ih      = (const float*)d_in[3];
    const float* W_hh      = (const float*)d_in[4];
    const float* b_ih      = (const float*)d_in[5];
    const float* b_hh      = (const float*)d_in[6];
    const float* W_lin     = (const float*)d_in[7];
    const float* b_lin     = (const float*)d_in[8];
    float* out = (float*)d_out;

    // ws layout
    char* ws = (char*)d_ws;
    unsigned long long* hbuf = (unsigned long long*)(ws);          // 131,072 B
    unsigned long long* dech = (unsigned long long*)(ws + 131072); // 1,245,184 B
    unsigned* flags = (unsigned*)(ws + 1376256);                   // 256 B
    short*    wbf   = (short*)(ws + 1376512);                      // 32,768,000 B
    float*    xpws  = (float*)(ws + 34144512);                     // 31,457,280 B
    const bool big  = ws_size >= (size_t)34144512;
    const bool bigx = ws_size >= (size_t)34144512 + 31457280;

    if (bigx) {
        // xs/wih live in d_out's tail: dead before consumers write out.
        // out_size = 155,648,000 B.
        short* xs  = (short*)((char*)d_out + 143589376);   // 7,864,320 B
        short* wih = (short*)((char*)d_out + 151453696);   // 4,194,304 B
        float* Xp  = xpws;

        prep_new<<<2048, 256, 0, stream>>>(
            feature, captions, embedding, W_ih, W_lin, xs, wih, wbf, flags);

        xproj_gemm<<<dim3(16, 30), 256, 0, stream>>>(xs, wih, b_ih, b_hh, Xp);

        mega<<<dim3(LSTM_BLOCKS + 2500), 256, 0, stream>>>(
            Xp, W_hh, hbuf, dech, flags, wbf, b_lin, out);
    } else {
        // fallback: r9 serial pipeline
        float* Xp = (float*)d_out;
        prep_old<<<dim3(big ? 8481 : 481), 256, 0, stream>>>(
            feature, captions, embedding, W_ih, b_ih, b_hh, Xp,
            W_lin, big ? wbf : (short*)nullptr, flags);
        mega<<<dim3(LSTM_BLOCKS), 256, 0, stream>>>(
            Xp, W_hh, hbuf, dech, flags, (const short*)nullptr, b_lin, out);
        if (big)
            gemm_out<true><<<dim3(250, 10), 256, 0, stream>>>(
                (const short*)dech, wbf, b_lin, out, 1216, 32000, 512);
        else
            gemm_out<false><<<dim3(250, 10), 256, 0, stream>>>(
                (const short*)dech, W_lin, b_lin, out, 1216, 32000, 512);
    }
}